// Round 1
// baseline (1085.769 us; speedup 1.0000x reference)
//
#include <hip/hip_runtime.h>
#include <stdint.h>

// RWKV TimeMix on MI355X.
// Pipeline: prep_xm (time-shift mix + bf16 hi/lo split) -> wsplit (weights hi/lo)
//   -> gemm_bt z=3 (k,v,r) -> mid (sigmoid/decay fuse, writes new_state + srns hi/lo)
//   -> gemm_bt z=1 (out).
// GEMMs use split-bf16 (A*B ~ Ah*Bh + Al*Bh + Ah*Bl) for ~fp32 accuracy at 3x bf16 cost.

#define DIM  2048
#define MTOT 8192   // B*T = 4*2048

typedef unsigned short u16;
typedef float f32x4 __attribute__((ext_vector_type(4)));
typedef __bf16 bf16x8 __attribute__((ext_vector_type(8)));

// ---------- helpers ----------

__device__ __forceinline__ void gload16(const void* g, void* l) {
  // async global->LDS, 16B per lane; LDS dest is wave-uniform base + lane*16
  __builtin_amdgcn_global_load_lds(
      (__attribute__((address_space(1))) void*)(uintptr_t)g,
      (__attribute__((address_space(3))) void*)l, 16, 0, 0);
}

__device__ __forceinline__ u16 f2bf(float v) {  // RNE f32->bf16
  unsigned u = __float_as_uint(v);
  return (u16)((u + 0x7fffu + ((u >> 16) & 1u)) >> 16);
}
__device__ __forceinline__ float bf2f(u16 h) {
  return __uint_as_float(((unsigned)h) << 16);
}
__device__ __forceinline__ void split2(float v, u16& h, u16& l) {
  h = f2bf(v);
  l = f2bf(v - bf2f(h));   // residual exact in f32; combined precision ~2^-17
}

// ---------- elementwise kernels ----------

// xm = x*tc + shift(x)*(1-tc); store hi/lo bf16. One thread = 4 elems.
__global__ __launch_bounds__(256) void prep_xm(
    const float* __restrict__ x, const float* __restrict__ tc,
    u16* __restrict__ xh, u16* __restrict__ xl) {
  long i4 = (long)blockIdx.x * 256 + threadIdx.x;
  long e0 = i4 * 4;
  int m  = (int)(e0 >> 11);      // row (b*T+t), D=2048
  int d0 = (int)(e0 & 2047);
  int t  = m & 2047;             // t within batch, T=2048
  float4 xv  = *(const float4*)(x + e0);
  float4 pv  = (t > 0) ? *(const float4*)(x + e0 - DIM)
                       : make_float4(0.f, 0.f, 0.f, 0.f);
  float4 tcv = *(const float4*)(tc + d0);
  float xm[4];
  xm[0] = xv.x * tcv.x + pv.x * (1.f - tcv.x);
  xm[1] = xv.y * tcv.y + pv.y * (1.f - tcv.y);
  xm[2] = xv.z * tcv.z + pv.z * (1.f - tcv.z);
  xm[3] = xv.w * tcv.w + pv.w * (1.f - tcv.w);
  u16 h[4], l[4];
  #pragma unroll
  for (int j = 0; j < 4; ++j) split2(xm[j], h[j], l[j]);
  *(ushort4*)(xh + e0) = make_ushort4(h[0], h[1], h[2], h[3]);
  *(ushort4*)(xl + e0) = make_ushort4(l[0], l[1], l[2], l[3]);
}

// split the 4 weight matrices into hi/lo bf16, concatenated [4][D*D]
__global__ __launch_bounds__(256) void wsplit(
    const float* __restrict__ W0, const float* __restrict__ W1,
    const float* __restrict__ W2, const float* __restrict__ W3,
    u16* __restrict__ wh, u16* __restrict__ wl) {
  long i4 = (long)blockIdx.x * 256 + threadIdx.x;
  long e0 = i4 * 4;
  int which = (int)(e0 >> 22);           // D*D = 2^22
  long off  = e0 & ((1L << 22) - 1);
  const float* W = which == 0 ? W0 : which == 1 ? W1 : which == 2 ? W2 : W3;
  float4 wv = *(const float4*)(W + off);
  u16 h[4], l[4];
  split2(wv.x, h[0], l[0]); split2(wv.y, h[1], l[1]);
  split2(wv.z, h[2], l[2]); split2(wv.w, h[3], l[3]);
  *(ushort4*)(wh + e0) = make_ushort4(h[0], h[1], h[2], h[3]);
  *(ushort4*)(wl + e0) = make_ushort4(l[0], l[1], l[2], l[3]);
}

// ns = k*v + decay*state -> d_out(new_state); srns = sigmoid(r)*ns -> hi/lo bf16
__global__ __launch_bounds__(256) void mid(
    const float* __restrict__ kb, const float* __restrict__ vb,
    const float* __restrict__ rb, const float* __restrict__ st,
    const float* __restrict__ td, float* __restrict__ ns,
    u16* __restrict__ sh, u16* __restrict__ sl) {
  long i4 = (long)blockIdx.x * 256 + threadIdx.x;
  long e0 = i4 * 4;
  int d0 = (int)(e0 & 2047);
  float4 k4 = *(const float4*)(kb + e0);
  float4 v4 = *(const float4*)(vb + e0);
  float4 r4 = *(const float4*)(rb + e0);
  float4 s4 = *(const float4*)(st + e0);
  float4 t4 = *(const float4*)(td + d0);
  float kk[4] = {k4.x, k4.y, k4.z, k4.w};
  float vv[4] = {v4.x, v4.y, v4.z, v4.w};
  float rr[4] = {r4.x, r4.y, r4.z, r4.w};
  float ss[4] = {s4.x, s4.y, s4.z, s4.w};
  float tt[4] = {t4.x, t4.y, t4.z, t4.w};
  float nn[4];
  u16 h[4], l[4];
  #pragma unroll
  for (int j = 0; j < 4; ++j) {
    float dec = expf(-expf(tt[j]));
    nn[j] = kk[j] * vv[j] + dec * ss[j];
    float sr = 1.f / (1.f + expf(-rr[j]));
    split2(sr * nn[j], h[j], l[j]);
  }
  *(float4*)(ns + e0)  = make_float4(nn[0], nn[1], nn[2], nn[3]);
  *(ushort4*)(sh + e0) = make_ushort4(h[0], h[1], h[2], h[3]);
  *(ushort4*)(sl + e0) = make_ushort4(l[0], l[1], l[2], l[3]);
}

// ---------- split-bf16 GEMM: C[m,e] = sum_d A[m,d]*B[e,d] ----------
// 128x128 tile, BK=32, 4 waves (2x2), per-wave 64x64 via 4x4 16x16x32 MFMA frags.
// LDS swizzle: linear dest for global_load_lds + pre-swizzled GLOBAL source
// (granule g ^= (row>>1)&3) + matching swizzled ds_read (rule #21 / T2-lite):
// turns the 8-way bank conflict of [128][32]bf16 rows into 2-way (free, m136).
__global__ __launch_bounds__(256, 2) void gemm_bt(
    const u16* __restrict__ Ah, const u16* __restrict__ Al,
    const u16* __restrict__ Bh, const u16* __restrict__ Bl,
    float* __restrict__ C, long zsB, long zsC) {
  const int z = blockIdx.z;
  Bh += (long)z * zsB; Bl += (long)z * zsB; C += (long)z * zsC;

  __shared__ u16 sAh[128 * 32], sAl[128 * 32], sBh[128 * 32], sBl[128 * 32];

  const int tid  = threadIdx.x;
  const int lane = tid & 63;
  const int wave = tid >> 6;
  const int wr = wave >> 1, wc = wave & 1;
  const long bm = (long)blockIdx.y * 128;
  const long bn = (long)blockIdx.x * 128;

  // staging: granule p in [0,512), 16B each; row=p>>2, logical granule g^swizzle
  const int p0 = tid, p1 = 256 + tid;
  const int row0 = p0 >> 2, row1 = p1 >> 2;
  const int g0 = (p0 & 3) ^ ((p0 >> 3) & 3);
  const int g1 = (p1 & 3) ^ ((p1 >> 3) & 3);
  const long aoff0 = (bm + row0) * DIM + g0 * 8;
  const long aoff1 = (bm + row1) * DIM + g1 * 8;
  const long boff0 = (bn + row0) * DIM + g0 * 8;
  const long boff1 = (bn + row1) * DIM + g1 * 8;

  // fragment reads: lane holds 8 contiguous k at chunk (lane>>4), row (lane&15)
  const int rlo = lane & 15;
  const int sw  = (rlo >> 1) & 3;                 // (row>>1)&3, i-independent
  const int gk  = ((lane >> 4) ^ sw) * 8;         // swizzled k-chunk offset (elems)
  const int arow = wr * 64 + rlo;
  const int brow = wc * 64 + rlo;

  f32x4 acc[4][4] = {};

  for (int kt = 0; kt < DIM / 32; ++kt) {
    const int kc = kt * 32;
    gload16(Ah + aoff0 + kc, sAh + p0 * 8);
    gload16(Ah + aoff1 + kc, sAh + p1 * 8);
    gload16(Al + aoff0 + kc, sAl + p0 * 8);
    gload16(Al + aoff1 + kc, sAl + p1 * 8);
    gload16(Bh + boff0 + kc, sBh + p0 * 8);
    gload16(Bh + boff1 + kc, sBh + p1 * 8);
    gload16(Bl + boff0 + kc, sBl + p0 * 8);
    gload16(Bl + boff1 + kc, sBl + p1 * 8);
    __syncthreads();   // compiler emits vmcnt(0) drain before s_barrier

    bf16x8 ah[4], al[4], bh[4], bl[4];
    #pragma unroll
    for (int i = 0; i < 4; ++i) {
      ah[i] = *(const bf16x8*)(sAh + (arow + i * 16) * 32 + gk);
      al[i] = *(const bf16x8*)(sAl + (arow + i * 16) * 32 + gk);
    }
    #pragma unroll
    for (int j = 0; j < 4; ++j) {
      bh[j] = *(const bf16x8*)(sBh + (brow + j * 16) * 32 + gk);
      bl[j] = *(const bf16x8*)(sBl + (brow + j * 16) * 32 + gk);
    }
    #pragma unroll
    for (int i = 0; i < 4; ++i)
      #pragma unroll
      for (int j = 0; j < 4; ++j) {
        acc[i][j] = __builtin_amdgcn_mfma_f32_16x16x32_bf16(ah[i], bh[j], acc[i][j], 0, 0, 0);
        acc[i][j] = __builtin_amdgcn_mfma_f32_16x16x32_bf16(al[i], bh[j], acc[i][j], 0, 0, 0);
        acc[i][j] = __builtin_amdgcn_mfma_f32_16x16x32_bf16(ah[i], bl[j], acc[i][j], 0, 0, 0);
      }
    __syncthreads();
  }

  // C/D layout (m89-verified): col = lane&15, row = (lane>>4)*4 + reg
  const int col = lane & 15;
  const int rg  = (lane >> 4) * 4;
  #pragma unroll
  for (int i = 0; i < 4; ++i)
    #pragma unroll
    for (int j = 0; j < 4; ++j) {
      f32x4 v = acc[i][j];
      long gm = bm + wr * 64 + i * 16 + rg;
      long gn = bn + wc * 64 + j * 16 + col;
      #pragma unroll
      for (int r = 0; r < 4; ++r) C[(gm + r) * DIM + gn] = v[r];
    }
}

// ---------- host ----------

extern "C" void kernel_launch(void* const* d_in, const int* in_sizes, int n_in,
                              void* d_out, int out_size, void* d_ws, size_t ws_size,
                              hipStream_t stream) {
  (void)in_sizes; (void)n_in; (void)out_size;
  const float* x  = (const float*)d_in[0];
  const float* st = (const float*)d_in[1];
  const float* Wk = (const float*)d_in[2];
  const float* Wv = (const float*)d_in[3];
  const float* Wr = (const float*)d_in[4];
  const float* Wo = (const float*)d_in[5];
  const float* td = (const float*)d_in[6];
  const float* tc = (const float*)d_in[7];

  const long MD = (long)MTOT * DIM;   // 16,777,216
  const long DD = (long)DIM * DIM;    // 4,194,304

  // ws layout: xm hi/lo (reused for srns hi/lo) | weights hi/lo | k,v,r chunk
  u16* xh = (u16*)d_ws;
  u16* xl = xh + MD;
  u16* wh = xl + MD;
  u16* wl = wh + 4 * DD;
  float* kvr = (float*)(wl + 4 * DD);
  const size_t fixed = (size_t)(2 * MD + 8 * DD) * sizeof(u16);  // 128 MiB

  // chunk M so 3 f32 scratch buffers fit ws_size
  int nc = 1;
  while (nc < 32 && fixed + (size_t)3 * (MTOT / nc) * DIM * 4 > ws_size) nc <<= 1;
  const long Mc = MTOT / nc;

  float* out = (float*)d_out;        // [MD] out
  float* nso = out + MD;             // [MD] new_state

  prep_xm<<<dim3(MD / 4 / 256), dim3(256), 0, stream>>>(x, tc, xh, xl);
  wsplit<<<dim3(4 * DD / 4 / 256), dim3(256), 0, stream>>>(Wk, Wv, Wr, Wo, wh, wl);
  for (int c = 0; c < nc; ++c) {
    long mo = (long)c * Mc * DIM;
    gemm_bt<<<dim3(DIM / 128, Mc / 128, 3), dim3(256), 0, stream>>>(
        xh + mo, xl + mo, wh, wl, kvr, DD, Mc * (long)DIM);
    mid<<<dim3(Mc * DIM / 4 / 256), dim3(256), 0, stream>>>(
        kvr, kvr + Mc * DIM, kvr + 2 * Mc * DIM, st + mo, td,
        nso + mo, xh + mo, xl + mo);
  }
  gemm_bt<<<dim3(DIM / 128, MTOT / 128, 1), dim3(256), 0, stream>>>(
      xh, xl, wh + 3 * DD, wl + 3 * DD, out, 0, 0);
}

// Round 3
// 1039.566 us; speedup vs baseline: 1.0444x; 1.0444x over previous
//
#include <hip/hip_runtime.h>
#include <stdint.h>

// RWKV TimeMix on MI355X.
// prep_xm (shift-mix + bf16 hi/lo split) -> wsplit -> gemm8 z-fused (k|v|r, N=6144)
//   -> mid (sigmoid/decay fuse) -> gemm8 (out).
// GEMM: split-bf16 (Ah*Bh + Al*Bh + Ah*Bl), 256x128 tile, BK=32, 8 waves,
// triple-buffered LDS, 4-phase/K-tile schedule with counted vmcnt (T3+T4),
// setprio around MFMA (T5), XCD swizzle (T1), XOR-granule LDS swizzle (T2, 0-conflict).

#define DIM  2048
#define MTOT 8192   // B*T
#define BM 256
#define BN 128
#define BK 32
#define KT (DIM / BK)              // 64
#define NTHR 512
#define ASZ (BM * BK)              // u16 elems (16KB)
#define BSZ (BN * BK)              // u16 elems (8KB)
#define BUFSZ (2 * ASZ + 2 * BSZ)  // 24576 elems (48KB)
#define LDS_BYTES (3 * BUFSZ * 2)  // 147456

typedef unsigned short u16;
typedef float f32x4 __attribute__((ext_vector_type(4)));
typedef __bf16 bf16x8 __attribute__((ext_vector_type(8)));

// ---------- helpers ----------

__device__ __forceinline__ void gload16(const void* g, void* l) {
  // async global->LDS, 16B/lane; LDS dest = wave-uniform base + lane*16
  __builtin_amdgcn_global_load_lds(
      (__attribute__((address_space(1))) void*)(uintptr_t)g,
      (__attribute__((address_space(3))) void*)l, 16, 0, 0);
}

__device__ __forceinline__ u16 f2bf(float v) {  // RNE f32->bf16
  unsigned u = __float_as_uint(v);
  return (u16)((u + 0x7fffu + ((u >> 16) & 1u)) >> 16);
}
__device__ __forceinline__ float bf2f(u16 h) {
  return __uint_as_float(((unsigned)h) << 16);
}
__device__ __forceinline__ void split2(float v, u16& h, u16& l) {
  h = f2bf(v);
  l = f2bf(v - bf2f(h));   // combined precision ~2^-17
}

// ---------- elementwise kernels ----------

__global__ __launch_bounds__(256) void prep_xm(
    const float* __restrict__ x, const float* __restrict__ tc,
    u16* __restrict__ xh, u16* __restrict__ xl) {
  long i4 = (long)blockIdx.x * 256 + threadIdx.x;
  long e0 = i4 * 4;
  int d0 = (int)(e0 & 2047);
  int m  = (int)(e0 >> 11);
  int t  = m & 2047;
  float4 xv  = *(const float4*)(x + e0);
  float4 pv  = (t > 0) ? *(const float4*)(x + e0 - DIM)
                       : make_float4(0.f, 0.f, 0.f, 0.f);
  float4 tcv = *(const float4*)(tc + d0);
  float xm[4];
  xm[0] = xv.x * tcv.x + pv.x * (1.f - tcv.x);
  xm[1] = xv.y * tcv.y + pv.y * (1.f - tcv.y);
  xm[2] = xv.z * tcv.z + pv.z * (1.f - tcv.z);
  xm[3] = xv.w * tcv.w + pv.w * (1.f - tcv.w);
  u16 h[4], l[4];
  #pragma unroll
  for (int j = 0; j < 4; ++j) split2(xm[j], h[j], l[j]);
  *(ushort4*)(xh + e0) = make_ushort4(h[0], h[1], h[2], h[3]);
  *(ushort4*)(xl + e0) = make_ushort4(l[0], l[1], l[2], l[3]);
}

__global__ __launch_bounds__(256) void wsplit(
    const float* __restrict__ W0, const float* __restrict__ W1,
    const float* __restrict__ W2, const float* __restrict__ W3,
    u16* __restrict__ wh, u16* __restrict__ wl) {
  long i4 = (long)blockIdx.x * 256 + threadIdx.x;
  long e0 = i4 * 4;
  int which = (int)(e0 >> 22);
  long off  = e0 & ((1L << 22) - 1);
  const float* W = which == 0 ? W0 : which == 1 ? W1 : which == 2 ? W2 : W3;
  float4 wv = *(const float4*)(W + off);
  u16 h[4], l[4];
  split2(wv.x, h[0], l[0]); split2(wv.y, h[1], l[1]);
  split2(wv.z, h[2], l[2]); split2(wv.w, h[3], l[3]);
  *(ushort4*)(wh + e0) = make_ushort4(h[0], h[1], h[2], h[3]);
  *(ushort4*)(wl + e0) = make_ushort4(l[0], l[1], l[2], l[3]);
}

__global__ __launch_bounds__(256) void mid(
    const float* __restrict__ kb, const float* __restrict__ vb,
    const float* __restrict__ rb, const float* __restrict__ st,
    const float* __restrict__ td, float* __restrict__ ns,
    u16* __restrict__ sh, u16* __restrict__ sl) {
  long i4 = (long)blockIdx.x * 256 + threadIdx.x;
  long e0 = i4 * 4;
  int d0 = (int)(e0 & 2047);
  float4 k4 = *(const float4*)(kb + e0);
  float4 v4 = *(const float4*)(vb + e0);
  float4 r4 = *(const float4*)(rb + e0);
  float4 s4 = *(const float4*)(st + e0);
  float4 t4 = *(const float4*)(td + d0);
  float kk[4] = {k4.x, k4.y, k4.z, k4.w};
  float vv[4] = {v4.x, v4.y, v4.z, v4.w};
  float rr[4] = {r4.x, r4.y, r4.z, r4.w};
  float ss[4] = {s4.x, s4.y, s4.z, s4.w};
  float tt[4] = {t4.x, t4.y, t4.z, t4.w};
  float nn[4];
  u16 h[4], l[4];
  #pragma unroll
  for (int j = 0; j < 4; ++j) {
    float dec = expf(-expf(tt[j]));
    nn[j] = kk[j] * vv[j] + dec * ss[j];
    float sr = 1.f / (1.f + expf(-rr[j]));
    split2(sr * nn[j], h[j], l[j]);
  }
  *(float4*)(ns + e0)  = make_float4(nn[0], nn[1], nn[2], nn[3]);
  *(ushort4*)(sh + e0) = make_ushort4(h[0], h[1], h[2], h[3]);
  *(ushort4*)(sl + e0) = make_ushort4(l[0], l[1], l[2], l[3]);
}

// ---------- split-bf16 GEMM, 4-phase counted-vmcnt schedule ----------
// C[m,e] = sum_d A[m,d]*B[e,d]; 8 waves (2M x 4N), per-wave 128x32 output.

__global__ __launch_bounds__(NTHR, 2) void gemm8(
    const u16* __restrict__ Ah, const u16* __restrict__ Al,
    const u16* __restrict__ Bh, const u16* __restrict__ Bl,
    float* __restrict__ C, int NB, int nwg, int kvr, long zsC) {
  extern __shared__ u16 lds[];

  // T1: bijective XCD swizzle (nwg % 8 == 0 in all our launches)
  const int bid = blockIdx.x;
  const int wg  = (bid & 7) * (nwg >> 3) + (bid >> 3);
  const int mb  = wg / NB, nb = wg - mb * NB;
  const long bm = (long)mb * BM;
  const long bn = (long)nb * BN;

  const int tid  = threadIdx.x;
  const int lane = tid & 63;
  const int wave = tid >> 6;
  const int wr = wave >> 2, wc = wave & 3;

  // staging: 16B granules; row = p>>2, source granule XOR-swizzled (T2 via
  // pre-swizzled global src + linear LDS dest, rule #21)
  const int pa0 = tid, pa1 = tid + NTHR;
  const long aS0 = (bm + (pa0 >> 2)) * (long)DIM + ((pa0 & 3) ^ ((pa0 >> 3) & 3)) * 8;
  const long aS1 = (bm + (pa1 >> 2)) * (long)DIM + ((pa1 & 3) ^ ((pa1 >> 3) & 3)) * 8;
  const long bS0 = (bn + (pa0 >> 2)) * (long)DIM + ((pa0 & 3) ^ ((pa0 >> 3) & 3)) * 8;
  const int dA0 = pa0 * 8, dA1 = pa1 * 8;  // LDS elem offset within plane

  #define STAGE_AH(bsel, kc) { u16* L = lds + (bsel) * BUFSZ; \
      gload16(Ah + aS0 + (kc), L + dA0); gload16(Ah + aS1 + (kc), L + dA1); }
  #define STAGE_AL(bsel, kc) { u16* L = lds + (bsel) * BUFSZ + ASZ; \
      gload16(Al + aS0 + (kc), L + dA0); gload16(Al + aS1 + (kc), L + dA1); }
  #define STAGE_B(bsel, kc)  { u16* L = lds + (bsel) * BUFSZ + 2 * ASZ; \
      gload16(Bh + bS0 + (kc), L + dA0); gload16(Bl + bS0 + (kc), L + BSZ + dA0); }

  // fragment reads: row rlo within 16-row frag, swizzled k-chunk
  const int rlo  = lane & 15;
  const int gk   = (((lane >> 4) ^ ((rlo >> 1) & 3)) << 3);
  const int arow = wr * 128 + rlo;
  const int brow = wc * 32 + rlo;

  f32x4 acc[8][2] = {};

  // prologue: stage tiles 0 and 1 (6 loads each), wait tile 0
  STAGE_AH(0, 0) STAGE_AL(0, 0) STAGE_B(0, 0)
  STAGE_AH(1, BK) STAGE_AL(1, BK) STAGE_B(1, BK)
  asm volatile("s_waitcnt vmcnt(6)" ::: "memory");
  __builtin_amdgcn_s_barrier();

  int cur = 0;
  #pragma unroll 1
  for (int t = 0; t < KT; ++t) {
    const u16* LA_h = lds + cur * BUFSZ;
    const u16* LA_l = LA_h + ASZ;
    const u16* LB_h = LA_h + 2 * ASZ;
    const u16* LB_l = LB_h + BSZ;
    int nx2 = cur + 2; if (nx2 >= 3) nx2 -= 3;
    const bool st = (t + 2) < KT;
    const int kc = (t + 2) * BK;
    bf16x8 bh[2], bl[2];
    #pragma unroll
    for (int q = 0; q < 4; ++q) {
      bf16x8 ah[2], al[2];
      #pragma unroll
      for (int i2 = 0; i2 < 2; ++i2) {
        const int ro = (arow + (2 * q + i2) * 16) * BK + gk;
        ah[i2] = *(const bf16x8*)(LA_h + ro);
        al[i2] = *(const bf16x8*)(LA_l + ro);
      }
      if (q == 0) {
        #pragma unroll
        for (int j = 0; j < 2; ++j) {
          const int ro = (brow + j * 16) * BK + gk;
          bh[j] = *(const bf16x8*)(LB_h + ro);
          bl[j] = *(const bf16x8*)(LB_l + ro);
        }
      }
      if (st) {
        if (q == 0)      STAGE_AH(nx2, kc)
        else if (q == 1) STAGE_AL(nx2, kc)
        else if (q == 2) STAGE_B(nx2, kc)
      }
      __builtin_amdgcn_s_barrier();
      asm volatile("s_waitcnt lgkmcnt(0)" ::: "memory");
      __builtin_amdgcn_s_setprio(1);
      #pragma unroll
      for (int i2 = 0; i2 < 2; ++i2)
        #pragma unroll
        for (int j = 0; j < 2; ++j) {
          f32x4 a = acc[2 * q + i2][j];
          a = __builtin_amdgcn_mfma_f32_16x16x32_bf16(ah[i2], bh[j], a, 0, 0, 0);
          a = __builtin_amdgcn_mfma_f32_16x16x32_bf16(al[i2], bh[j], a, 0, 0, 0);
          a = __builtin_amdgcn_mfma_f32_16x16x32_bf16(ah[i2], bl[j], a, 0, 0, 0);
          acc[2 * q + i2][j] = a;
        }
      __builtin_amdgcn_s_setprio(0);
      if (q == 3) {  // boundary: t+1's loads must have landed; t+2's stay in flight
        if (st) asm volatile("s_waitcnt vmcnt(6)" ::: "memory");
        else    asm volatile("s_waitcnt vmcnt(0)" ::: "memory");
      }
      __builtin_amdgcn_s_barrier();
    }
    cur += 1; if (cur == 3) cur = 0;
  }

  // C/D layout (m89): col = lane&15, row = (lane>>4)*4 + reg
  const int col = lane & 15;
  const int rg  = (lane >> 4) * 4;
  long cb;
  if (kvr) cb = (long)(bn >> 11) * zsC + (bn & 2047);  // split N=6144 -> k|v|r
  else     cb = bn;
  float* Co = C + cb;
  #pragma unroll
  for (int i = 0; i < 8; ++i)
    #pragma unroll
    for (int j = 0; j < 2; ++j) {
      long gm = bm + wr * 128 + i * 16 + rg;
      int  gn = wc * 32 + j * 16 + col;
      f32x4 v = acc[i][j];
      #pragma unroll
      for (int rr = 0; rr < 4; ++rr) Co[(gm + rr) * DIM + gn] = v[rr];
    }
  #undef STAGE_AH
  #undef STAGE_AL
  #undef STAGE_B
}

// ---------- host ----------

extern "C" void kernel_launch(void* const* d_in, const int* in_sizes, int n_in,
                              void* d_out, int out_size, void* d_ws, size_t ws_size,
                              hipStream_t stream) {
  (void)in_sizes; (void)n_in; (void)out_size;
  const float* x  = (const float*)d_in[0];
  const float* st = (const float*)d_in[1];
  const float* Wk = (const float*)d_in[2];
  const float* Wv = (const float*)d_in[3];
  const float* Wr = (const float*)d_in[4];
  const float* Wo = (const float*)d_in[5];
  const float* td = (const float*)d_in[6];
  const float* tc = (const float*)d_in[7];

  const long MD = (long)MTOT * DIM;
  const long DD = (long)DIM * DIM;

  u16* xh = (u16*)d_ws;
  u16* xl = xh + MD;
  u16* wh = xl + MD;
  u16* wl = wh + 4 * DD;
  float* kvr = (float*)(wl + 4 * DD);
  const size_t fixed = (size_t)(2 * MD + 8 * DD) * sizeof(u16);

  int nc = 1;
  while (nc < 32 && fixed + (size_t)3 * (MTOT / nc) * DIM * 4 > ws_size) nc <<= 1;
  const long Mc = MTOT / nc;

  float* out = (float*)d_out;
  float* nso = out + MD;

  hipFuncSetAttribute((const void*)gemm8,
                      hipFuncAttributeMaxDynamicSharedMemorySize, LDS_BYTES);

  prep_xm<<<dim3(MD / 4 / 256), dim3(256), 0, stream>>>(x, tc, xh, xl);
  wsplit<<<dim3(4 * DD / 4 / 256), dim3(256), 0, stream>>>(Wk, Wv, Wr, Wo, wh, wl);
  for (int c = 0; c < nc; ++c) {
    long mo = (long)c * Mc * DIM;
    const int nwgK = (int)(Mc / BM) * (3 * DIM / BN);   // %8==0 for all nc
    gemm8<<<dim3(nwgK), dim3(NTHR), LDS_BYTES, stream>>>(
        xh + mo, xl + mo, wh, wl, kvr, 3 * DIM / BN, nwgK, 1, Mc * (long)DIM);
    mid<<<dim3(Mc * DIM / 4 / 256), dim3(256), 0, stream>>>(
        kvr, kvr + Mc * DIM, kvr + 2 * Mc * DIM, st + mo, td,
        nso + mo, xh + mo, xl + mo);
  }
  const int nwgO = (MTOT / BM) * (DIM / BN);            // 512
  gemm8<<<dim3(nwgO), dim3(NTHR), LDS_BYTES, stream>>>(
      xh, xl, wh + 3 * DD, wl + 3 * DD, out, DIM / BN, nwgO, 0, 0);
}

// Round 8
// 949.073 us; speedup vs baseline: 1.1440x; 1.0953x over previous
//
#include <hip/hip_runtime.h>
#include <stdint.h>

// RWKV TimeMix on MI355X.
// prep_xm (shift-mix + bf16 hi/lo split) -> wsplit -> gemm8 z-fused (k|v|r, N=6144)
//   -> mid (sigmoid/decay fuse) -> gemm8 (out).
// GEMM: split-bf16 (Ah*Bh + Al*Bh + Ah*Bl), 256x256 tile, BK=32, 8 waves (2Mx4N),
// per-wave 128x64 (8x4 frags of 16x16x32), double-buffered LDS (2x64KB),
// 4 quadrant-phases per K-tile (24 MFMA each), stage-early + boundary vmcnt,
// setprio (T5), XCD swizzle (T1), XOR-granule LDS swizzle (T2, 0-conflict).

#define DIM  2048
#define MTOT 8192   // B*T
#define BM 256
#define BN 256
#define BK 32
#define KT (DIM / BK)              // 64
#define NTHR 512
#define PLANE (BM * BK)            // 8192 u16 elems (16KB) per plane
#define BUFSZ (4 * PLANE)          // Ah|Al|Bh|Bl = 32768 elems (64KB)
#define LDS_BYTES (2 * BUFSZ * 2)  // 131072

typedef unsigned short u16;
typedef float f32x4 __attribute__((ext_vector_type(4)));
typedef __bf16 bf16x8 __attribute__((ext_vector_type(8)));

// ---------- helpers ----------

__device__ __forceinline__ void gload16(const void* g, void* l) {
  __builtin_amdgcn_global_load_lds(
      (__attribute__((address_space(1))) void*)(uintptr_t)g,
      (__attribute__((address_space(3))) void*)l, 16, 0, 0);
}

__device__ __forceinline__ u16 f2bf(float v) {  // RNE f32->bf16
  unsigned u = __float_as_uint(v);
  return (u16)((u + 0x7fffu + ((u >> 16) & 1u)) >> 16);
}
__device__ __forceinline__ float bf2f(u16 h) {
  return __uint_as_float(((unsigned)h) << 16);
}
__device__ __forceinline__ void split2(float v, u16& h, u16& l) {
  h = f2bf(v);
  l = f2bf(v - bf2f(h));   // combined precision ~2^-17
}

// ---------- elementwise kernels (unchanged, verified R1/R3) ----------

__global__ __launch_bounds__(256) void prep_xm(
    const float* __restrict__ x, const float* __restrict__ tc,
    u16* __restrict__ xh, u16* __restrict__ xl) {
  long i4 = (long)blockIdx.x * 256 + threadIdx.x;
  long e0 = i4 * 4;
  int d0 = (int)(e0 & 2047);
  int m  = (int)(e0 >> 11);
  int t  = m & 2047;
  float4 xv  = *(const float4*)(x + e0);
  float4 pv  = (t > 0) ? *(const float4*)(x + e0 - DIM)
                       : make_float4(0.f, 0.f, 0.f, 0.f);
  float4 tcv = *(const float4*)(tc + d0);
  float xm[4];
  xm[0] = xv.x * tcv.x + pv.x * (1.f - tcv.x);
  xm[1] = xv.y * tcv.y + pv.y * (1.f - tcv.y);
  xm[2] = xv.z * tcv.z + pv.z * (1.f - tcv.z);
  xm[3] = xv.w * tcv.w + pv.w * (1.f - tcv.w);
  u16 h[4], l[4];
  #pragma unroll
  for (int j = 0; j < 4; ++j) split2(xm[j], h[j], l[j]);
  *(ushort4*)(xh + e0) = make_ushort4(h[0], h[1], h[2], h[3]);
  *(ushort4*)(xl + e0) = make_ushort4(l[0], l[1], l[2], l[3]);
}

__global__ __launch_bounds__(256) void wsplit(
    const float* __restrict__ W0, const float* __restrict__ W1,
    const float* __restrict__ W2, const float* __restrict__ W3,
    u16* __restrict__ wh, u16* __restrict__ wl) {
  long i4 = (long)blockIdx.x * 256 + threadIdx.x;
  long e0 = i4 * 4;
  int which = (int)(e0 >> 22);
  long off  = e0 & ((1L << 22) - 1);
  const float* W = which == 0 ? W0 : which == 1 ? W1 : which == 2 ? W2 : W3;
  float4 wv = *(const float4*)(W + off);
  u16 h[4], l[4];
  split2(wv.x, h[0], l[0]); split2(wv.y, h[1], l[1]);
  split2(wv.z, h[2], l[2]); split2(wv.w, h[3], l[3]);
  *(ushort4*)(wh + e0) = make_ushort4(h[0], h[1], h[2], h[3]);
  *(ushort4*)(wl + e0) = make_ushort4(l[0], l[1], l[2], l[3]);
}

__global__ __launch_bounds__(256) void mid(
    const float* __restrict__ kb, const float* __restrict__ vb,
    const float* __restrict__ rb, const float* __restrict__ st,
    const float* __restrict__ td, float* __restrict__ ns,
    u16* __restrict__ sh, u16* __restrict__ sl) {
  long i4 = (long)blockIdx.x * 256 + threadIdx.x;
  long e0 = i4 * 4;
  int d0 = (int)(e0 & 2047);
  float4 k4 = *(const float4*)(kb + e0);
  float4 v4 = *(const float4*)(vb + e0);
  float4 r4 = *(const float4*)(rb + e0);
  float4 s4 = *(const float4*)(st + e0);
  float4 t4 = *(const float4*)(td + d0);
  float kk[4] = {k4.x, k4.y, k4.z, k4.w};
  float vv[4] = {v4.x, v4.y, v4.z, v4.w};
  float rr[4] = {r4.x, r4.y, r4.z, r4.w};
  float ss[4] = {s4.x, s4.y, s4.z, s4.w};
  float tt[4] = {t4.x, t4.y, t4.z, t4.w};
  float nn[4];
  u16 h[4], l[4];
  #pragma unroll
  for (int j = 0; j < 4; ++j) {
    float dec = expf(-expf(tt[j]));
    nn[j] = kk[j] * vv[j] + dec * ss[j];
    float sr = 1.f / (1.f + expf(-rr[j]));
    split2(sr * nn[j], h[j], l[j]);
  }
  *(float4*)(ns + e0)  = make_float4(nn[0], nn[1], nn[2], nn[3]);
  *(ushort4*)(sh + e0) = make_ushort4(h[0], h[1], h[2], h[3]);
  *(ushort4*)(sl + e0) = make_ushort4(l[0], l[1], l[2], l[3]);
}

// ---------- GEMM inner helpers ----------

__device__ __forceinline__ bf16x8 frd(const u16* plane, int r, int gko) {
  return *(const bf16x8*)(plane + r * BK + gko);
}

__device__ __forceinline__ void mfma_blk(f32x4 (&acc)[8][4], int ib, int jb,
    const bf16x8 (&ah)[4], const bf16x8 (&al)[4],
    const bf16x8 (&bh)[2], const bf16x8 (&bl)[2]) {
  #pragma unroll
  for (int i = 0; i < 4; ++i)
    #pragma unroll
    for (int j = 0; j < 2; ++j) {
      f32x4 a = acc[ib + i][jb + j];
      a = __builtin_amdgcn_mfma_f32_16x16x32_bf16(ah[i], bh[j], a, 0, 0, 0);
      a = __builtin_amdgcn_mfma_f32_16x16x32_bf16(al[i], bh[j], a, 0, 0, 0);
      a = __builtin_amdgcn_mfma_f32_16x16x32_bf16(ah[i], bl[j], a, 0, 0, 0);
      acc[ib + i][jb + j] = a;
    }
}

#define PHASE_SYNC() do { \
    __builtin_amdgcn_s_barrier(); \
    asm volatile("s_waitcnt lgkmcnt(0)" ::: "memory"); \
    __builtin_amdgcn_sched_barrier(0); \
  } while (0)

// ---------- split-bf16 GEMM: C[m,e] = sum_d A[m,d]*B[e,d] ----------

__global__ __launch_bounds__(NTHR, 2) void gemm8(
    const u16* __restrict__ Ah, const u16* __restrict__ Al,
    const u16* __restrict__ Bh, const u16* __restrict__ Bl,
    float* __restrict__ C, int NB, int nwg, int kvr, long zsC) {
  extern __shared__ u16 lds[];

  // T1: bijective XCD swizzle (nwg % 8 == 0 in all launches)
  const int bid = blockIdx.x;
  const int wg  = (bid & 7) * (nwg >> 3) + (bid >> 3);
  const int mb  = wg / NB, nb = wg - mb * NB;
  const long bm = (long)mb * BM;
  const long bn = (long)nb * BN;

  const int tid  = threadIdx.x;
  const int lane = tid & 63;
  const int wave = tid >> 6;
  const int wr = wave >> 2, wc = wave & 3;

  // staging: plane = 256 rows x 4 granules(16B) = 1024 granules, 2 per thread.
  // granule p: row = p>>2, src granule XOR-swizzled (T2: pre-swizzled global
  // src + linear LDS dest, rule #21). Note ((row+128)>>1)&3 == (row>>1)&3.
  const int row0 = tid >> 2;
  const int gsw  = ((tid & 3) ^ ((row0 >> 1) & 3)) * 8;   // elems
  const long aS0 = (bm + row0) * (long)DIM + gsw;
  const long aS1 = (bm + row0 + 128) * (long)DIM + gsw;
  const long bS0 = (bn + row0) * (long)DIM + gsw;
  const long bS1 = (bn + row0 + 128) * (long)DIM + gsw;
  const int d0 = tid * 8, d1 = (tid + NTHR) * 8;          // LDS elem offsets

  #define STAGE_A(bsel, kc) { u16* L = lds + (bsel) * BUFSZ; \
      gload16(Ah + aS0 + (kc), L + d0);         gload16(Ah + aS1 + (kc), L + d1); \
      gload16(Al + aS0 + (kc), L + PLANE + d0); gload16(Al + aS1 + (kc), L + PLANE + d1); }
  #define STAGE_B(bsel, kc) { u16* L = lds + (bsel) * BUFSZ + 2 * PLANE; \
      gload16(Bh + bS0 + (kc), L + d0);         gload16(Bh + bS1 + (kc), L + d1); \
      gload16(Bl + bS0 + (kc), L + PLANE + d0); gload16(Bl + bS1 + (kc), L + PLANE + d1); }

  // fragment reads: row r, k-chunk (lane>>4) XOR row-key (r>>1)&3 == (rlo>>1)&3
  const int rlo  = lane & 15;
  const int gko  = (((lane >> 4) ^ ((rlo >> 1) & 3)) << 3);
  const int ab   = wr * 128 + rlo;   // A row base (frag i at ab + i*16)
  const int bb   = wc * 64 + rlo;    // B row base (frag j at bb + j*16)

  f32x4 acc[8][4] = {};

  // prologue: stage tile 0, drain once
  STAGE_A(0, 0) STAGE_B(0, 0)
  asm volatile("s_waitcnt vmcnt(0)" ::: "memory");
  __builtin_amdgcn_s_barrier();

  #pragma unroll 1
  for (int t = 0; t < KT; ++t) {
    const int cur = t & 1;
    const u16* LAh = lds + cur * BUFSZ;
    const u16* LAl = LAh + PLANE;
    const u16* LBh = LAh + 2 * PLANE;
    const u16* LBl = LAh + 3 * PLANE;
    const int nx = cur ^ 1;
    const bool st = (t + 1) < KT;
    const int kc = (t + 1) * BK;

    bf16x8 ah[4], al[4], bh0[2], bl0[2], bh1[2], bl1[2];

    // ---- phase 0: A-half0 x B-half0 ----
    #pragma unroll
    for (int i = 0; i < 4; ++i) {
      ah[i] = frd(LAh, ab + i * 16, gko);
      al[i] = frd(LAl, ab + i * 16, gko);
    }
    #pragma unroll
    for (int j = 0; j < 2; ++j) {
      bh0[j] = frd(LBh, bb + j * 16, gko);
      bl0[j] = frd(LBl, bb + j * 16, gko);
    }
    if (st) STAGE_A(nx, kc)
    PHASE_SYNC();
    __builtin_amdgcn_s_setprio(1);
    mfma_blk(acc, 0, 0, ah, al, bh0, bl0);
    __builtin_amdgcn_s_setprio(0);
    __builtin_amdgcn_s_barrier();

    // ---- phase 1: A-half0 x B-half1 ----
    #pragma unroll
    for (int j = 0; j < 2; ++j) {
      bh1[j] = frd(LBh, bb + (2 + j) * 16, gko);
      bl1[j] = frd(LBl, bb + (2 + j) * 16, gko);
    }
    if (st) STAGE_B(nx, kc)
    PHASE_SYNC();
    __builtin_amdgcn_s_setprio(1);
    mfma_blk(acc, 0, 2, ah, al, bh1, bl1);
    __builtin_amdgcn_s_setprio(0);
    __builtin_amdgcn_s_barrier();

    // ---- phase 2: A-half1 x B-half1 ----
    #pragma unroll
    for (int i = 0; i < 4; ++i) {
      ah[i] = frd(LAh, ab + (4 + i) * 16, gko);
      al[i] = frd(LAl, ab + (4 + i) * 16, gko);
    }
    PHASE_SYNC();
    __builtin_amdgcn_s_setprio(1);
    mfma_blk(acc, 4, 2, ah, al, bh1, bl1);
    __builtin_amdgcn_s_setprio(0);
    __builtin_amdgcn_s_barrier();

    // ---- phase 3: A-half1 x B-half0 (no reads) ----
    __builtin_amdgcn_s_setprio(1);
    mfma_blk(acc, 4, 0, ah, al, bh0, bl0);
    __builtin_amdgcn_s_setprio(0);
    if (st) asm volatile("s_waitcnt vmcnt(0)" ::: "memory");
    __builtin_amdgcn_s_barrier();
  }

  // C/D layout (m89): col = lane&15, row = (lane>>4)*4 + reg
  const int col = lane & 15;
  const int rg  = (lane >> 4) * 4;
  long cb;
  if (kvr) cb = (long)(bn >> 11) * zsC + (bn & 2047);  // split N=6144 -> k|v|r
  else     cb = bn;
  float* Co = C + cb;
  #pragma unroll
  for (int i = 0; i < 8; ++i)
    #pragma unroll
    for (int j = 0; j < 4; ++j) {
      long gm = bm + wr * 128 + i * 16 + rg;
      int  gn = wc * 64 + j * 16 + col;
      f32x4 v = acc[i][j];
      #pragma unroll
      for (int rr = 0; rr < 4; ++rr) Co[(gm + rr) * DIM + gn] = v[rr];
    }
  #undef STAGE_A
  #undef STAGE_B
}

// ---------- host ----------

extern "C" void kernel_launch(void* const* d_in, const int* in_sizes, int n_in,
                              void* d_out, int out_size, void* d_ws, size_t ws_size,
                              hipStream_t stream) {
  (void)in_sizes; (void)n_in; (void)out_size;
  const float* x  = (const float*)d_in[0];
  const float* st = (const float*)d_in[1];
  const float* Wk = (const float*)d_in[2];
  const float* Wv = (const float*)d_in[3];
  const float* Wr = (const float*)d_in[4];
  const float* Wo = (const float*)d_in[5];
  const float* td = (const float*)d_in[6];
  const float* tc = (const float*)d_in[7];

  const long MD = (long)MTOT * DIM;
  const long DD = (long)DIM * DIM;

  u16* xh = (u16*)d_ws;
  u16* xl = xh + MD;
  u16* wh = xl + MD;
  u16* wl = wh + 4 * DD;
  float* kvr = (float*)(wl + 4 * DD);
  const size_t fixed = (size_t)(2 * MD + 8 * DD) * sizeof(u16);

  int nc = 1;
  while (nc < 32 && fixed + (size_t)3 * (MTOT / nc) * DIM * 4 > ws_size) nc <<= 1;
  const long Mc = MTOT / nc;

  float* out = (float*)d_out;
  float* nso = out + MD;

  hipFuncSetAttribute((const void*)gemm8,
                      hipFuncAttributeMaxDynamicSharedMemorySize, LDS_BYTES);

  prep_xm<<<dim3(MD / 4 / 256), dim3(256), 0, stream>>>(x, tc, xh, xl);
  wsplit<<<dim3(4 * DD / 4 / 256), dim3(256), 0, stream>>>(Wk, Wv, Wr, Wo, wh, wl);
  for (int c = 0; c < nc; ++c) {
    long mo = (long)c * Mc * DIM;
    const int nwgK = (int)(Mc / BM) * (3 * DIM / BN);   // %8==0 for all nc
    gemm8<<<dim3(nwgK), dim3(NTHR), LDS_BYTES, stream>>>(
        xh + mo, xl + mo, wh, wl, kvr, 3 * DIM / BN, nwgK, 1, Mc * (long)DIM);
    mid<<<dim3(Mc * DIM / 4 / 256), dim3(256), 0, stream>>>(
        kvr, kvr + Mc * DIM, kvr + 2 * Mc * DIM, st + mo, td,
        nso + mo, xh + mo, xl + mo);
  }
  const int nwgO = (MTOT / BM) * (DIM / BN);            // 256
  gemm8<<<dim3(nwgO), dim3(NTHR), LDS_BYTES, stream>>>(
      xh, xl, wh + 3 * DD, wl + 3 * DD, out, DIM / BN, nwgO, 0, 0);
}